// Round 3
// baseline (2102.064 us; speedup 1.0000x reference)
//
#include <hip/hip_runtime.h>
#include <hip/hip_bf16.h>
#include <cstdint>

using bf16 = __hip_bfloat16;
using bf16x8 = __attribute__((ext_vector_type(8))) short;   // 8 bf16 = 4 VGPRs
using f32x4  = __attribute__((ext_vector_type(4))) float;

#define NHEADS 8
#define SEQ 49
#define CDIM 448
#define PDIM 1024

// ======================= split-path constants =================================
#define MROWS 100352          // 2048*49, == 784*128 exactly
#define MTILES 784
#define NTILES 12             // 1536/128
#define AQKS 72   // attn q/k LDS row stride, elems (144B rows: 16B-aligned, 36dw==4 mod 32 -> 2-way)
#define AVTS 72   // attn vT row stride
#define ACS 136   // attn ctx row stride (272B rows: aligned; 68dw==4 mod 32 -> 2-way)
#define OLS 136   // qkv-gemm output-stage row stride

// attn LDS layout (byte offsets, 16B aligned)
static constexpr int SM2_CTX = 0;                    // 64*136*2 = 17408
static constexpr int SM2_QK  = 17408;                // 49*72*2  = 7056 -> 7072
static constexpr int SM2_VT  = 24480;                // 128*72*2 = 18432
static constexpr int SM2_AB  = 42912;                // 392*4    = 1568
static constexpr int SM2_SZ  = 44480;

static constexpr size_t OFF_QKV   = 64;              // [0..3] = dtype flag
static constexpr size_t QKV_BYTES = (size_t)MROWS * 1536 * 2;   // 308,281,344
static constexpr size_t WS_SPLIT  = OFF_QKV + QKV_BYTES;

// ======================= fallback-path constants (round-2) ====================
#define QS 36
#define VTS 68
#define CS 132
static constexpr int SM_CTX = 0;
static constexpr int SM_QL  = 16896;
static constexpr int SM_KL  = 21504;
static constexpr int SM_VT  = 26112;
static constexpr int SM_AB  = 43520;
static constexpr int SM_SZ  = 45088;

static constexpr size_t kNhs = (size_t)2048 * SEQ * CDIM;
static constexpr size_t kNqw = (size_t)1536 * CDIM;
static constexpr size_t kNqb = 1536;
static constexpr size_t kNpw = (size_t)CDIM * PDIM;
static constexpr size_t kNpb = CDIM;
static constexpr size_t kNab = NHEADS * SEQ;
static constexpr size_t OFF_HS = 64;
static constexpr size_t OFF_QW = OFF_HS + kNhs * 2;
static constexpr size_t OFF_QB = OFF_QW + kNqw * 2;
static constexpr size_t OFF_PW = OFF_QB + kNqb * 2;
static constexpr size_t OFF_PB = OFF_PW + kNpw * 2;
static constexpr size_t OFF_AB = OFF_PB + kNpb * 2;
static constexpr size_t WS_NEEDED = OFF_AB + kNab * 2;

// ======================= helpers ==============================================
__device__ __forceinline__ short f2s(float x) {
    union { bf16 h; short s; } u; u.h = __float2bfloat16(x); return u.s;
}
__device__ __forceinline__ bf16x8 load8(const bf16* p) { return *(const bf16x8*)p; }
__device__ __forceinline__ bf16x8 load8(const float* p) {
    f32x4 a = *(const f32x4*)p;
    f32x4 b = *(const f32x4*)(p + 4);
    bf16x8 r;
    r[0]=f2s(a[0]); r[1]=f2s(a[1]); r[2]=f2s(a[2]); r[3]=f2s(a[3]);
    r[4]=f2s(b[0]); r[5]=f2s(b[1]); r[6]=f2s(b[2]); r[7]=f2s(b[3]);
    return r;
}
__device__ __forceinline__ float toF(bf16 x) { return __bfloat162float(x); }
__device__ __forceinline__ float toF(float x) { return x; }
__device__ __forceinline__ void storeT(bf16* p, float v) { *p = __float2bfloat16(v); }
__device__ __forceinline__ void storeT(float* p, float v) { *p = v; }

// ======================= kernel 1: QKV GEMM (split path) ======================
// qkv[100352][1536] (bf16, ws) = hs[100352][448] @ qkv_w[1536][448]^T + qkv_b
// grid 9408 = 784 mtiles x 12 ntiles (bn = bid/784 so consecutive blocks share
// the B panel; hs streams once per ntile, L3-resident after first pass).
template <typename T>
__device__ __forceinline__
void qkv_gemm_body(const T* __restrict__ hs, const T* __restrict__ qw,
                   const T* __restrict__ qb, bf16* __restrict__ qkv, bf16* ol) {
    const int bid = blockIdx.x;
    const int bn  = bid / MTILES;
    const int bm  = bid - bn * MTILES;
    const int tid = threadIdx.x;
    const int l   = tid & 63;
    const int w   = tid >> 6;
    const int wm  = w >> 1, wn = w & 1;
    const int lr  = l & 15;
    const int lk  = (l >> 4) * 8;
    const int cm  = (l >> 4) * 4;
    const int cn  = l & 15;

    const size_t r0 = (size_t)bm * 128 + wm * 64;   // wave rows (all real)
    const int    c0 = bn * 128 + wn * 64;           // wave cols

    f32x4 acc[4][4] = {};   // [mf][nf]
    bf16x8 afA[4], bfA[4], afB[4], bfB[4];

    auto LOADG = [&](int ks, bf16x8* af, bf16x8* bfr) {
        const int k0 = ks * 32;
        #pragma unroll
        for (int mf = 0; mf < 4; ++mf)
            af[mf] = load8(hs + (r0 + 16 * mf + lr) * CDIM + k0 + lk);
        #pragma unroll
        for (int nf = 0; nf < 4; ++nf)
            bfr[nf] = load8(qw + (size_t)(c0 + 16 * nf + lr) * CDIM + k0 + lk);
    };
    auto MM = [&](bf16x8* af, bf16x8* bfr) {
        #pragma unroll
        for (int mf = 0; mf < 4; ++mf)
            #pragma unroll
            for (int nf = 0; nf < 4; ++nf)
                acc[mf][nf] = __builtin_amdgcn_mfma_f32_16x16x32_bf16(
                    af[mf], bfr[nf], acc[mf][nf], 0, 0, 0);
    };

    LOADG(0, afA, bfA);
    LOADG(1, afB, bfB);
    #pragma unroll
    for (int ks = 0; ks < 14; ks += 2) {
        MM(afA, bfA);
        if (ks + 2 < 14) LOADG(ks + 2, afA, bfA);
        MM(afB, bfB);
        if (ks + 3 < 14) LOADG(ks + 3, afB, bfB);
    }

    // epilogue: +bias -> LDS (bf16) -> coalesced 16B global stores
    float bv[4];
    #pragma unroll
    for (int nf = 0; nf < 4; ++nf)
        bv[nf] = toF(qb[c0 + 16 * nf + cn]);
    #pragma unroll
    for (int mf = 0; mf < 4; ++mf)
        #pragma unroll
        for (int nf = 0; nf < 4; ++nf)
            #pragma unroll
            for (int r = 0; r < 4; ++r)
                ol[(wm * 64 + 16 * mf + cm + r) * OLS + wn * 64 + 16 * nf + cn] =
                    __float2bfloat16(acc[mf][nf][r] + bv[nf]);
    __syncthreads();
    for (int p = tid; p < 2048; p += 256) {
        const int row = p >> 4, c16 = p & 15;
        *(int4*)(qkv + ((size_t)bm * 128 + row) * 1536 + bn * 128 + c16 * 8) =
            *(const int4*)(ol + row * OLS + c16 * 8);
    }
}

__global__ __launch_bounds__(256, 2)
void qkv_gemm_k(const void* hs, const void* qw, const void* qb,
                unsigned char* ws) {
    __shared__ __align__(16) bf16 ol[128 * OLS];
    bf16* qkv = (bf16*)(ws + OFF_QKV);
    if (*(const int*)ws)
        qkv_gemm_body<float>((const float*)hs, (const float*)qw,
                             (const float*)qb, qkv, ol);
    else
        qkv_gemm_body<bf16>((const bf16*)hs, (const bf16*)qw,
                            (const bf16*)qb, qkv, ol);
}

// ======================= kernel 2: attn + proj (split path) ===================
// Per block = one batch, 4 waves, 2 barriers/head. q/k/v for head h+1 are
// register-staged: global loads issued BEFORE phase D's MFMAs, LDS writes after
// (T14 async-split: HBM latency hides under proj MFMAs).
template <typename T, typename TO>
__device__ __forceinline__
void attn_body(const bf16* __restrict__ qkv, const T* __restrict__ proj_w,
               const T* __restrict__ proj_b, const T* __restrict__ ab,
               TO* __restrict__ out, char* smem) {
    bf16*  ctxp = (bf16*)(smem + SM2_CTX);
    bf16*  qkl  = (bf16*)(smem + SM2_QK);
    bf16*  vtl  = (bf16*)(smem + SM2_VT);
    float* abl  = (float*)(smem + SM2_AB);

    const int b   = blockIdx.x;
    const int tid = threadIdx.x;
    const int l   = tid & 63;
    const int w   = tid >> 6;
    const int lr  = l & 15;
    const int lk  = (l >> 4) * 8;
    const int cm  = (l >> 4) * 4;
    const int cn  = l & 15;

    for (int i = tid; i < NHEADS * SEQ; i += 256) abl[i] = toF(ab[i]);
    // zero vT pad tokens 49..63 once (P pad cols are 0, but 0*NaN = NaN)
    for (int i = tid; i < 128 * (64 - SEQ); i += 256) {
        const int d = i / (64 - SEQ), t = SEQ + i % (64 - SEQ);
        vtl[d * AVTS + t] = __float2bfloat16(0.f);
    }

    // bias index: idx = |r1-r2|*7 + |c1-c2|, token t -> (t/7, t%7)
    int rq[4], rr[4], cq[4], cr[4];
    #pragma unroll
    for (int r = 0; r < 4; ++r) {
        int row = 16 * w + cm + r; if (row > SEQ - 1) row = SEQ - 1;
        rq[r] = (row * 37) >> 8; rr[r] = row - rq[r] * 7;
    }
    #pragma unroll
    for (int j = 0; j < 4; ++j) {
        int col = 16 * j + cn; if (col > SEQ - 1) col = 0;
        cq[j] = (col * 37) >> 8; cr[j] = col - cq[j] * 7;
    }

    const bf16* qb = qkv + (size_t)b * SEQ * 1536;

    // ---- register staging of head hh's q/k (49x64) and v (49x128) ----
    int4 qs0, qs1, vs0, vs1, vs2, vs3;
    auto STAGE_LOAD = [&](int hh) {
        const bf16* hb = qb + hh * 192;
        { const int p = tid;       const int t = p >> 3, c = p & 7;
          qs0 = *(const int4*)(hb + (size_t)t * 1536 + c * 8); }
        { const int p = tid + 256; if (p < 392) { const int t = p >> 3, c = p & 7;
          qs1 = *(const int4*)(hb + (size_t)t * 1536 + c * 8); } }
        { const int p = tid;       const int t = p >> 4, c = p & 15;
          vs0 = *(const int4*)(hb + (size_t)t * 1536 + 64 + c * 8); }
        { const int p = tid + 256; const int t = p >> 4, c = p & 15;
          vs1 = *(const int4*)(hb + (size_t)t * 1536 + 64 + c * 8); }
        { const int p = tid + 512; const int t = p >> 4, c = p & 15;
          vs2 = *(const int4*)(hb + (size_t)t * 1536 + 64 + c * 8); }
        { const int p = tid + 768; if (p < 784) { const int t = p >> 4, c = p & 15;
          vs3 = *(const int4*)(hb + (size_t)t * 1536 + 64 + c * 8); } }
    };
    auto WRV = [&](int p, int4 v) {
        const int t = p >> 4, c = p & 15;
        bf16 tmp[8]; *(int4*)tmp = v;
        #pragma unroll
        for (int j = 0; j < 8; ++j) vtl[(c * 8 + j) * AVTS + t] = tmp[j];
    };
    auto STAGE_WRITE = [&]() {
        { const int p = tid;       const int t = p >> 3, c = p & 7;
          *(int4*)(qkl + t * AQKS + c * 8) = qs0; }
        { const int p = tid + 256; if (p < 392) { const int t = p >> 3, c = p & 7;
          *(int4*)(qkl + t * AQKS + c * 8) = qs1; } }
        WRV(tid, vs0); WRV(tid + 256, vs1); WRV(tid + 512, vs2);
        if (tid < 16) WRV(tid + 768, vs3);
    };

    f32x4 oacc[4][7] = {};
    const float scale = 0.17677669529663687f;

    STAGE_LOAD(0);
    STAGE_WRITE();
    __syncthreads();   // B1(0)

    for (int h = 0; h < NHEADS; ++h) {
        // ========= Phase B: scores MFMA + softmax; P -> own ctx rows (cols 0..63)
        {
            const int qrow = (16 * w + lr < SEQ) ? 16 * w + lr : SEQ - 1;
            const bf16x8 aq = *(const bf16x8*)(qkl + qrow * AQKS + lk);
            f32x4 sacc[4] = {};
            #pragma unroll
            for (int j = 0; j < 4; ++j) {
                const int krow = (16 * j + lr < SEQ) ? 16 * j + lr : SEQ - 1;
                const bf16x8 kb = *(const bf16x8*)(qkl + krow * AQKS + 32 + lk);
                sacc[j] = __builtin_amdgcn_mfma_f32_16x16x32_bf16(
                    aq, kb, sacc[j], 0, 0, 0);
            }
            #pragma unroll
            for (int r = 0; r < 4; ++r) {
                const int row = 16 * w + cm + r;
                float v[4], e[4];
                float m = -3.0e38f;
                #pragma unroll
                for (int j = 0; j < 4; ++j) {
                    const int col = 16 * j + cn;
                    if (col < SEQ) {
                        int dy = rq[r] - cq[j]; dy = dy < 0 ? -dy : dy;
                        int dx = rr[r] - cr[j]; dx = dx < 0 ? -dx : dx;
                        v[j] = sacc[j][r] * scale + abl[h * SEQ + dy * 7 + dx];
                        m = fmaxf(m, v[j]);
                    } else v[j] = -3.0e38f;
                }
                m = fmaxf(m, __shfl_xor(m, 1));
                m = fmaxf(m, __shfl_xor(m, 2));
                m = fmaxf(m, __shfl_xor(m, 4));
                m = fmaxf(m, __shfl_xor(m, 8));
                float s = 0.f;
                #pragma unroll
                for (int j = 0; j < 4; ++j) {
                    e[j] = (16 * j + cn < SEQ) ? __expf(v[j] - m) : 0.f;
                    s += e[j];
                }
                s += __shfl_xor(s, 1);
                s += __shfl_xor(s, 2);
                s += __shfl_xor(s, 4);
                s += __shfl_xor(s, 8);
                const float inv = 1.f / s;
                #pragma unroll
                for (int j = 0; j < 4; ++j)
                    ctxp[row * ACS + 16 * j + cn] = __float2bfloat16(e[j] * inv);
            }
        }
        // no barrier: P writes/reads are wave-private rows

        // ========= Phase C: PV MFMA; overwrite own ctx rows
        {
            const bf16x8 pa0 = *(const bf16x8*)(ctxp + (16 * w + lr) * ACS + lk);
            const bf16x8 pa1 = *(const bf16x8*)(ctxp + (16 * w + lr) * ACS + 32 + lk);
            f32x4 cacc[8] = {};
            #pragma unroll
            for (int n = 0; n < 8; ++n) {
                const bf16x8 vb = *(const bf16x8*)(vtl + (16 * n + lr) * AVTS + lk);
                cacc[n] = __builtin_amdgcn_mfma_f32_16x16x32_bf16(
                    pa0, vb, cacc[n], 0, 0, 0);
            }
            #pragma unroll
            for (int n = 0; n < 8; ++n) {
                const bf16x8 vb = *(const bf16x8*)(vtl + (16 * n + lr) * AVTS + 32 + lk);
                cacc[n] = __builtin_amdgcn_mfma_f32_16x16x32_bf16(
                    pa1, vb, cacc[n], 0, 0, 0);
            }
            #pragma unroll
            for (int n = 0; n < 8; ++n)
                #pragma unroll
                for (int r = 0; r < 4; ++r)
                    ctxp[(16 * w + cm + r) * ACS + 16 * n + cn] =
                        __float2bfloat16(cacc[n][r]);
        }
        __syncthreads();   // B3: ctx ready; q/k/vT free for restaging

        // ========= Phase D: proj partial + async restage of head h+1
        if (h + 1 < NHEADS) STAGE_LOAD(h + 1);   // loads fly under D's MFMAs
        #pragma unroll
        for (int ks3 = 0; ks3 < 4; ++ks3) {
            bf16x8 bw[7], ac[4];
            #pragma unroll
            for (int j = 0; j < 7; ++j) {
                const int n = (w * 7 + j) * 16 + lr;
                bw[j] = load8(proj_w + (size_t)n * PDIM + h * 128 + ks3 * 32 + lk);
            }
            #pragma unroll
            for (int mf = 0; mf < 4; ++mf)
                ac[mf] = *(const bf16x8*)(ctxp + (16 * mf + lr) * ACS + ks3 * 32 + lk);
            #pragma unroll
            for (int mf = 0; mf < 4; ++mf)
                #pragma unroll
                for (int j = 0; j < 7; ++j)
                    oacc[mf][j] = __builtin_amdgcn_mfma_f32_16x16x32_bf16(
                        ac[mf], bw[j], oacc[mf][j], 0, 0, 0);
        }
        if (h + 1 < NHEADS) {
            STAGE_WRITE();
            __syncthreads();   // B1(h+1): staging done; also orders ctx anti-dep
        }
    }

    // ========= store: out[b*49+row][col] = oacc + proj_b
    #pragma unroll
    for (int j = 0; j < 7; ++j) {
        const int col = w * 112 + j * 16 + cn;
        const float pbv = toF(proj_b[col]);
        #pragma unroll
        for (int mf = 0; mf < 4; ++mf)
            #pragma unroll
            for (int r = 0; r < 4; ++r) {
                const int row = 16 * mf + cm + r;
                if (row < SEQ)
                    storeT(out + ((size_t)b * SEQ + row) * CDIM + col,
                           oacc[mf][j][r] + pbv);
            }
    }
}

__global__ __launch_bounds__(256, 2)
void attn_proj_k(const void* proj_w, const void* proj_b, const void* ab,
                 void* out, unsigned char* ws) {
    __shared__ __align__(16) char smem[SM2_SZ];
    const bf16* qkv = (const bf16*)(ws + OFF_QKV);
    if (*(const int*)ws)
        attn_body<float, float>(qkv, (const float*)proj_w, (const float*)proj_b,
                                (const float*)ab, (float*)out, smem);
    else
        attn_body<bf16, bf16>(qkv, (const bf16*)proj_w, (const bf16*)proj_b,
                              (const bf16*)ab, (bf16*)out, smem);
}

// ======================= fallback path (round-2 fused kernel) =================
__device__ __forceinline__ void cvt_arr(const float* __restrict__ src,
                                        bf16* __restrict__ dst, size_t n4,
                                        size_t tid, size_t np) {
    for (size_t i = tid; i < n4; i += np) {
        f32x4 v = ((const f32x4*)src)[i];
        short4 o;
        o.x = f2s(v[0]); o.y = f2s(v[1]); o.z = f2s(v[2]); o.w = f2s(v[3]);
        ((short4*)dst)[i] = o;
    }
}

__global__ void convert_inputs(const float* hs, const float* qw, const float* qb,
                               const float* pw, const float* pb, const float* ab,
                               unsigned char* ws, const int* flag) {
    if (*flag == 0) return;
    const size_t tid = (size_t)blockIdx.x * blockDim.x + threadIdx.x;
    const size_t np  = (size_t)gridDim.x * blockDim.x;
    cvt_arr(hs, (bf16*)(ws + OFF_HS), kNhs / 4, tid, np);
    cvt_arr(qw, (bf16*)(ws + OFF_QW), kNqw / 4, tid, np);
    cvt_arr(qb, (bf16*)(ws + OFF_QB), kNqb / 4, tid, np);
    cvt_arr(pw, (bf16*)(ws + OFF_PW), kNpw / 4, tid, np);
    cvt_arr(pb, (bf16*)(ws + OFF_PB), kNpb / 4, tid, np);
    cvt_arr(ab, (bf16*)(ws + OFF_AB), kNab / 4, tid, np);
}

template <typename T, typename TO>
__device__ __forceinline__
void body(const T* __restrict__ hs, const T* __restrict__ qkv_w,
          const T* __restrict__ qkv_b, const T* __restrict__ proj_w,
          const T* __restrict__ proj_b, const T* __restrict__ ab,
          TO* __restrict__ out, char* smem) {
    bf16*  ctxp = (bf16*)(smem + SM_CTX);
    bf16*  ql   = (bf16*)(smem + SM_QL);
    bf16*  kl   = (bf16*)(smem + SM_KL);
    bf16*  vtl  = (bf16*)(smem + SM_VT);
    float* abl  = (float*)(smem + SM_AB);

    const int b   = blockIdx.x;
    const int tid = threadIdx.x;
    const int l   = tid & 63;
    const int w   = tid >> 6;
    const int lr  = l & 15;
    const int lk  = (l >> 4) * 8;
    const int cm  = (l >> 4) * 4;
    const int cn  = l & 15;

    for (int i = tid; i < NHEADS * SEQ; i += 256) abl[i] = toF(ab[i]);
    for (int i = tid; i < 128 * (64 - SEQ); i += 256) {
        const int d = i / (64 - SEQ), t = SEQ + i % (64 - SEQ);
        vtl[d * VTS + t] = __float2bfloat16(0.f);
    }

    int rq[4], rr[4], cq[4], cr[4];
    #pragma unroll
    for (int r = 0; r < 4; ++r) {
        int row = 16 * w + cm + r; if (row > SEQ - 1) row = SEQ - 1;
        rq[r] = (row * 37) >> 8; rr[r] = row - rq[r] * 7;
    }
    #pragma unroll
    for (int j = 0; j < 4; ++j) {
        int col = 16 * j + cn; if (col > SEQ - 1) col = 0;
        cq[j] = (col * 37) >> 8; cr[j] = col - cq[j] * 7;
    }

    f32x4 oacc[4][7] = {};
    const float scale = 0.17677669529663687f;
    const T* hsb = hs + (size_t)b * SEQ * CDIM;

    for (int h = 0; h < NHEADS; ++h) {
        f32x4 qacc[3][4] = {};
        bf16x8 af0[4], bf0[3], af1[4], bf1[3];
        auto LOADA = [&](int ks, bf16x8* af, bf16x8* bfr) {
            const int k0 = ks * 32;
            #pragma unroll
            for (int mf = 0; mf < 4; ++mf) {
                int row = 16 * mf + lr; if (row > SEQ - 1) row = SEQ - 1;
                af[mf] = load8(hsb + row * CDIM + k0 + lk);
            }
            #pragma unroll
            for (int j = 0; j < 3; ++j) {
                const int n = h * 192 + (3 * w + j) * 16 + lr;
                bfr[j] = load8(qkv_w + (size_t)n * CDIM + k0 + lk);
            }
        };
        auto MFMAA = [&](bf16x8* af, bf16x8* bfr) {
            #pragma unroll
            for (int j = 0; j < 3; ++j)
                #pragma unroll
                for (int mf = 0; mf < 4; ++mf)
                    qacc[j][mf] = __builtin_amdgcn_mfma_f32_16x16x32_bf16(
                        af[mf], bfr[j], qacc[j][mf], 0, 0, 0);
        };
        LOADA(0, af0, bf0);
        LOADA(1, af1, bf1);
        #pragma unroll
        for (int ks = 0; ks < 14; ks += 2) {
            MFMAA(af0, bf0);
            if (ks + 2 < 14) LOADA(ks + 2, af0, bf0);
            MFMAA(af1, bf1);
            if (ks + 3 < 14) LOADA(ks + 3, af1, bf1);
        }
        #pragma unroll
        for (int j = 0; j < 3; ++j) {
            const int c = (3 * w + j) * 16 + cn;
            const float bv = toF(qkv_b[h * 192 + c]);
            #pragma unroll
            for (int mf = 0; mf < 4; ++mf)
                #pragma unroll
                for (int r = 0; r < 4; ++r) {
                    const int row = 16 * mf + cm + r;
                    const float v = qacc[j][mf][r] + bv;
                    if (row < SEQ) {
                        if (c < 32)      ql[row * QS + c] = __float2bfloat16(v);
                        else if (c < 64) kl[row * QS + (c - 32)] = __float2bfloat16(v);
                        else             vtl[(c - 64) * VTS + row] = __float2bfloat16(v);
                    }
                }
        }
        __syncthreads();

        {
            const bf16x8 aq = *(const bf16x8*)(ql + (16 * w + lr) * QS + lk);
            f32x4 sacc[4] = {};
            #pragma unroll
            for (int j = 0; j < 4; ++j) {
                const bf16x8 kb = *(const bf16x8*)(kl + (16 * j + lr) * QS + lk);
                sacc[j] = __builtin_amdgcn_mfma_f32_16x16x32_bf16(
                    aq, kb, sacc[j], 0, 0, 0);
            }
            #pragma unroll
            for (int r = 0; r < 4; ++r) {
                const int row = 16 * w + cm + r;
                float v[4], e[4];
                float m = -3.0e38f;
                #pragma unroll
                for (int j = 0; j < 4; ++j) {
                    const int col = 16 * j + cn;
                    if (col < SEQ) {
                        int dy = rq[r] - cq[j]; dy = dy < 0 ? -dy : dy;
                        int dx = rr[r] - cr[j]; dx = dx < 0 ? -dx : dx;
                        v[j] = sacc[j][r] * scale + abl[h * SEQ + dy * 7 + dx];
                        m = fmaxf(m, v[j]);
                    } else v[j] = -3.0e38f;
                }
                m = fmaxf(m, __shfl_xor(m, 1));
                m = fmaxf(m, __shfl_xor(m, 2));
                m = fmaxf(m, __shfl_xor(m, 4));
                m = fmaxf(m, __shfl_xor(m, 8));
                float s = 0.f;
                #pragma unroll
                for (int j = 0; j < 4; ++j) {
                    e[j] = (16 * j + cn < SEQ) ? __expf(v[j] - m) : 0.f;
                    s += e[j];
                }
                s += __shfl_xor(s, 1);
                s += __shfl_xor(s, 2);
                s += __shfl_xor(s, 4);
                s += __shfl_xor(s, 8);
                const float inv = 1.f / s;
                #pragma unroll
                for (int j = 0; j < 4; ++j)
                    ctxp[row * CS + 16 * j + cn] = __float2bfloat16(e[j] * inv);
            }
        }

        {
            const bf16x8 pa0 = *(const bf16x8*)(ctxp + (16 * w + lr) * CS + lk);
            const bf16x8 pa1 = *(const bf16x8*)(ctxp + (16 * w + lr) * CS + 32 + lk);
            f32x4 cacc[8] = {};
            #pragma unroll
            for (int n = 0; n < 8; ++n) {
                const bf16x8 vb0 = *(const bf16x8*)(vtl + (16 * n + lr) * VTS + lk);
                cacc[n] = __builtin_amdgcn_mfma_f32_16x16x32_bf16(
                    pa0, vb0, cacc[n], 0, 0, 0);
            }
            #pragma unroll
            for (int n = 0; n < 8; ++n) {
                const bf16x8 vb1 = *(const bf16x8*)(vtl + (16 * n + lr) * VTS + 32 + lk);
                cacc[n] = __builtin_amdgcn_mfma_f32_16x16x32_bf16(
                    pa1, vb1, cacc[n], 0, 0, 0);
            }
            #pragma unroll
            for (int n = 0; n < 8; ++n)
                #pragma unroll
                for (int r = 0; r < 4; ++r)
                    ctxp[(16 * w + cm + r) * CS + 16 * n + cn] =
                        __float2bfloat16(cacc[n][r]);
        }
        __syncthreads();

        #pragma unroll
        for (int ks3 = 0; ks3 < 4; ++ks3) {
            bf16x8 bw[7], ac[4];
            #pragma unroll
            for (int j = 0; j < 7; ++j) {
                const int n = (w * 7 + j) * 16 + lr;
                bw[j] = load8(proj_w + (size_t)n * PDIM + h * 128 + ks3 * 32 + lk);
            }
            #pragma unroll
            for (int mf = 0; mf < 4; ++mf)
                ac[mf] = *(const bf16x8*)(ctxp + (16 * mf + lr) * CS + ks3 * 32 + lk);
            #pragma unroll
            for (int mf = 0; mf < 4; ++mf)
                #pragma unroll
                for (int j = 0; j < 7; ++j)
                    oacc[mf][j] = __builtin_amdgcn_mfma_f32_16x16x32_bf16(
                        ac[mf], bw[j], oacc[mf][j], 0, 0, 0);
        }
    }

    #pragma unroll
    for (int j = 0; j < 7; ++j) {
        const int col = w * 112 + j * 16 + cn;
        const float pbv = toF(proj_b[col]);
        #pragma unroll
        for (int mf = 0; mf < 4; ++mf)
            #pragma unroll
            for (int r = 0; r < 4; ++r) {
                const int row = 16 * mf + cm + r;
                if (row < SEQ)
                    storeT(out + ((size_t)b * SEQ + row) * CDIM + col,
                           oacc[mf][j][r] + pbv);
            }
    }
}

__global__ void detect_dtype(const unsigned int* __restrict__ w, int* __restrict__ flag) {
    if (threadIdx.x == 0 && blockIdx.x == 0) {
        int cnt = 0;
        for (int i = 0; i < 256; ++i) {
            const unsigned e = (w[i] >> 7) & 0xFF;
            cnt += (e >= 0x40 && e <= 0x7D);
        }
        *flag = (cnt < 156) ? 1 : 0;   // 1 = fp32, 0 = bf16
    }
}

__global__ __launch_bounds__(256, 2)
void fused_effattn(const void* hs, const void* qkv_w, const void* qkv_b,
                   const void* proj_w, const void* proj_b, const void* ab,
                   const int* idxs, void* out, unsigned char* ws, int use_ws) {
    __shared__ __align__(16) char smem[SM_SZ];
    const int f = *(const int*)ws;
    if (f) {
        if (use_ws) {
            body<bf16, float>((const bf16*)(ws + OFF_HS), (const bf16*)(ws + OFF_QW),
                              (const bf16*)(ws + OFF_QB), (const bf16*)(ws + OFF_PW),
                              (const bf16*)(ws + OFF_PB), (const bf16*)(ws + OFF_AB),
                              (float*)out, smem);
        } else {
            body<float, float>((const float*)hs, (const float*)qkv_w,
                               (const float*)qkv_b, (const float*)proj_w,
                               (const float*)proj_b, (const float*)ab,
                               (float*)out, smem);
        }
    } else {
        body<bf16, bf16>((const bf16*)hs, (const bf16*)qkv_w, (const bf16*)qkv_b,
                         (const bf16*)proj_w, (const bf16*)proj_b, (const bf16*)ab,
                         (bf16*)out, smem);
    }
}

// ======================= launcher =============================================
extern "C" void kernel_launch(void* const* d_in, const int* in_sizes, int n_in,
                              void* d_out, int out_size, void* d_ws, size_t ws_size,
                              hipStream_t stream) {
    unsigned char* ws = (unsigned char*)d_ws;
    detect_dtype<<<1, 64, 0, stream>>>((const unsigned int*)d_in[1], (int*)ws);
    if (ws_size >= WS_SPLIT) {
        qkv_gemm_k<<<dim3(MTILES * NTILES), dim3(256), 0, stream>>>(
            d_in[0], d_in[1], d_in[2], ws);
        attn_proj_k<<<dim3(2048), dim3(256), 0, stream>>>(
            d_in[3], d_in[4], d_in[5], d_out, ws);
    } else {
        const int use_ws = (ws_size >= WS_NEEDED) ? 1 : 0;
        if (use_ws)
            convert_inputs<<<dim3(2048), dim3(256), 0, stream>>>(
                (const float*)d_in[0], (const float*)d_in[1], (const float*)d_in[2],
                (const float*)d_in[3], (const float*)d_in[4], (const float*)d_in[5],
                ws, (const int*)ws);
        fused_effattn<<<dim3(2048), dim3(256), 0, stream>>>(
            d_in[0], d_in[1], d_in[2], d_in[3], d_in[4], d_in[5],
            (const int*)d_in[6], d_out, ws, use_ws);
    }
}

// Round 5
// 2055.072 us; speedup vs baseline: 1.0229x; 1.0229x over previous
//
#include <hip/hip_runtime.h>
#include <hip/hip_bf16.h>
#include <cstdint>

using bf16 = __hip_bfloat16;
using bf16x8 = __attribute__((ext_vector_type(8))) short;   // 8 bf16 = 4 VGPRs
using f32x4  = __attribute__((ext_vector_type(4))) float;

#define NHEADS 8
#define SEQ 49
#define CDIM 448
#define PDIM 1024
#define HDIM 1536
#define NB 2048
#define TPAD 56        // vT token padding (112B rows, 16B-aligned)

// ======================= new-path ws layout ===================================
static constexpr size_t OFF_QK   = 64;                               // [0..3]=flag
static constexpr size_t QK_BYTES = (size_t)NB * SEQ * 512 * 2;       // 102,760,448
static constexpr size_t OFF_VT   = OFF_QK + QK_BYTES;
static constexpr size_t VT_BYTES = (size_t)NB * NHEADS * 128 * TPAD * 2; // 234,881,024
static constexpr size_t OFF_PW2  = OFF_VT + VT_BYTES;
static constexpr size_t OFF_QW2  = OFF_PW2 + (size_t)CDIM * PDIM * 2;
static constexpr size_t OFF_QB2  = OFF_QW2 + (size_t)HDIM * CDIM * 2;
static constexpr size_t OFF_PB2  = OFF_QB2 + 4096;
static constexpr size_t OFF_AB2  = OFF_PB2 + 1024;
static constexpr size_t WS_A     = OFF_AB2 + 1024;                   // ~324 MiB

// K1 geometry: 64x64 block tile, 4 waves of 32x32, K=448
#define K1_NT 24              // 1536/64
#define K1_MT 1568            // 100352/64
#define OLS1 72               // K1 LDS out-stage stride (36dw -> 2-way max)

// K2 LDS layout
#define ACS 136               // ctx stride (68dw == 4 mod 32 -> 2-way); P aliased cols 0..63
#define AVTS 72               // vT LDS stride (36dw -> 2-way)
static constexpr int SM2_CTX = 0;                 // 64*136*2  = 17408
static constexpr int SM2_VT  = 17408;             // 128*72*2  = 18432
static constexpr int SM2_AB  = 35840;             // 392*4     = 1568
static constexpr int SM2_SZ  = 37440;

// ======================= fallback-path constants (round-2) ====================
#define QS 36
#define VTS 68
#define CS 132
static constexpr int SM_CTX = 0;
static constexpr int SM_QL  = 16896;
static constexpr int SM_KL  = 21504;
static constexpr int SM_VT  = 26112;
static constexpr int SM_AB  = 43520;
static constexpr int SM_SZ  = 45088;

static constexpr size_t kNhs = (size_t)NB * SEQ * CDIM;
static constexpr size_t kNqw = (size_t)HDIM * CDIM;
static constexpr size_t kNqb = HDIM;
static constexpr size_t kNpw = (size_t)CDIM * PDIM;
static constexpr size_t kNpb = CDIM;
static constexpr size_t kNab = NHEADS * SEQ;
static constexpr size_t OFF_HS = 64;
static constexpr size_t OFF_QW = OFF_HS + kNhs * 2;
static constexpr size_t OFF_QB = OFF_QW + kNqw * 2;
static constexpr size_t OFF_PW = OFF_QB + kNqb * 2;
static constexpr size_t OFF_PB = OFF_PW + kNpw * 2;
static constexpr size_t OFF_AB = OFF_PB + kNpb * 2;
static constexpr size_t WS_NEEDED = OFF_AB + kNab * 2;

// ======================= helpers ==============================================
__device__ __forceinline__ short f2s(float x) {
    union { bf16 h; short s; } u; u.h = __float2bfloat16(x); return u.s;
}
__device__ __forceinline__ bf16x8 load8(const bf16* p) { return *(const bf16x8*)p; }
__device__ __forceinline__ bf16x8 load8(const float* p) {
    f32x4 a = *(const f32x4*)p;
    f32x4 b = *(const f32x4*)(p + 4);
    bf16x8 r;
    r[0]=f2s(a[0]); r[1]=f2s(a[1]); r[2]=f2s(a[2]); r[3]=f2s(a[3]);
    r[4]=f2s(b[0]); r[5]=f2s(b[1]); r[6]=f2s(b[2]); r[7]=f2s(b[3]);
    return r;
}
__device__ __forceinline__ float toF(bf16 x) { return __bfloat162float(x); }
__device__ __forceinline__ float toF(float x) { return x; }
__device__ __forceinline__ void storeT(bf16* p, float v) { *p = __float2bfloat16(v); }
__device__ __forceinline__ void storeT(float* p, float v) { *p = v; }

// ======================= dtype detect =========================================
__global__ void detect_dtype(const unsigned int* __restrict__ w, int* __restrict__ flag) {
    if (threadIdx.x == 0 && blockIdx.x == 0) {
        int cnt = 0;
        for (int i = 0; i < 256; ++i) {
            const unsigned e = (w[i] >> 7) & 0xFF;
            cnt += (e >= 0x40 && e <= 0x7D);
        }
        *flag = (cnt < 156) ? 1 : 0;   // 1 = fp32, 0 = bf16
    }
}

// ======================= prep: weights -> bf16 ws; zero vT pads ===============
template <typename T>
__device__ __forceinline__
void prep_body(const T* qw, const T* qb, const T* pw, const T* pb, const T* ab,
               unsigned char* ws) {
    const size_t tid = (size_t)blockIdx.x * blockDim.x + threadIdx.x;
    const size_t np  = (size_t)gridDim.x * blockDim.x;
    bf16* qwd = (bf16*)(ws + OFF_QW2);
    for (size_t i = tid; i < (size_t)HDIM * CDIM; i += np)
        qwd[i] = __float2bfloat16(toF(qw[i]));
    bf16* pwd = (bf16*)(ws + OFF_PW2);
    for (size_t i = tid; i < (size_t)CDIM * PDIM; i += np)
        pwd[i] = __float2bfloat16(toF(pw[i]));
    bf16* qbd = (bf16*)(ws + OFF_QB2);
    for (size_t i = tid; i < HDIM; i += np) qbd[i] = __float2bfloat16(toF(qb[i]));
    bf16* pbd = (bf16*)(ws + OFF_PB2);
    for (size_t i = tid; i < CDIM; i += np) pbd[i] = __float2bfloat16(toF(pb[i]));
    bf16* abd = (bf16*)(ws + OFF_AB2);
    for (size_t i = tid; i < NHEADS * SEQ; i += np)
        abd[i] = __float2bfloat16(toF(ab[i]));
    // zero vT pad tokens 49..55 for every (b,h,d) row
    bf16* vt = (bf16*)(ws + OFF_VT);
    const bf16 z = __float2bfloat16(0.f);
    for (size_t i = tid; i < (size_t)NB * NHEADS * 128; i += np) {
        bf16* rp = vt + i * TPAD;
        #pragma unroll
        for (int j = SEQ; j < TPAD; ++j) rp[j] = z;
    }
}

__global__ void prep_k(const void* qw, const void* qb, const void* pw,
                       const void* pb, const void* ab, unsigned char* ws) {
    if (*(const int*)ws)
        prep_body<float>((const float*)qw, (const float*)qb, (const float*)pw,
                         (const float*)pb, (const float*)ab, ws);
    else
        prep_body<bf16>((const bf16*)qw, (const bf16*)qb, (const bf16*)pw,
                        (const bf16*)pb, (const bf16*)ab, ws);
}

// ======================= K1: QKV GEMM, routed epilogue ========================
// out rows g=0..100351 (= b*49+t), cols 0..1535. Routed stores:
//   per-head qk buffer [g][h][64] and transposed vT [b][h][d=128][TPAD].
// grid: bm-major (bm=bid/24) so 24 consecutive blocks share one hs A-panel.
template <typename T>
__device__ __forceinline__
void qkv1_body(const T* __restrict__ hs, unsigned char* ws, bf16* ol) {
    const bf16* qw = (const bf16*)(ws + OFF_QW2);
    const bf16* qb = (const bf16*)(ws + OFF_QB2);
    bf16* qk = (bf16*)(ws + OFF_QK);
    bf16* vt = (bf16*)(ws + OFF_VT);

    const int bid = blockIdx.x;
    const int bn  = bid % K1_NT;
    const int bm  = bid / K1_NT;
    const int tid = threadIdx.x, l = tid & 63, w = tid >> 6;
    const int wm  = w >> 1, wn = w & 1;
    const int lr  = l & 15, lk = (l >> 4) * 8;
    const int cm  = (l >> 4) * 4, cn = l & 15;

    const size_t r0 = (size_t)bm * 64 + wm * 32;
    const int    c0 = bn * 64 + wn * 32;

    f32x4 acc[2][2] = {};
    bf16x8 aA[2], bA[2], aB[2], bB[2];

    auto LOADG = [&](int ks, bf16x8* a, bf16x8* bb) {
        const int k0 = ks * 32;
        #pragma unroll
        for (int mf = 0; mf < 2; ++mf)
            a[mf] = load8(hs + (r0 + 16 * mf + lr) * CDIM + k0 + lk);
        #pragma unroll
        for (int nf = 0; nf < 2; ++nf)
            bb[nf] = load8(qw + (size_t)(c0 + 16 * nf + lr) * CDIM + k0 + lk);
    };
    auto MM = [&](bf16x8* a, bf16x8* bb) {
        #pragma unroll
        for (int mf = 0; mf < 2; ++mf)
            #pragma unroll
            for (int nf = 0; nf < 2; ++nf)
                acc[mf][nf] = __builtin_amdgcn_mfma_f32_16x16x32_bf16(
                    a[mf], bb[nf], acc[mf][nf], 0, 0, 0);
    };

    LOADG(0, aA, bA);
    LOADG(1, aB, bB);
    #pragma unroll
    for (int ks = 0; ks < 14; ks += 2) {
        MM(aA, bA);
        if (ks + 2 < 14) LOADG(ks + 2, aA, bA);
        MM(aB, bB);
        if (ks + 3 < 14) LOADG(ks + 3, aB, bB);
    }

    // +bias -> LDS tile [64][OLS1]
    float bv[2];
    #pragma unroll
    for (int nf = 0; nf < 2; ++nf) bv[nf] = toF(qb[c0 + 16 * nf + cn]);
    #pragma unroll
    for (int mf = 0; mf < 2; ++mf)
        #pragma unroll
        for (int nf = 0; nf < 2; ++nf)
            #pragma unroll
            for (int r = 0; r < 4; ++r)
                ol[(wm * 32 + 16 * mf + cm + r) * OLS1 + wn * 32 + 16 * nf + cn] =
                    __float2bfloat16(acc[mf][nf][r] + bv[nf]);
    __syncthreads();

    // q/k columns (r<64 within head chunk): coalesced int4 stores
    for (int i = tid; i < 512; i += 256) {
        const int row = i >> 3, cg = i & 7;
        const int c0g = bn * 64 + cg * 8;
        const int h = (unsigned)c0g / 192u;
        const int r = c0g - h * 192;
        if (r < 64) {
            const size_t g = (size_t)bm * 64 + row;
            *(int4*)(qk + g * 512 + h * 64 + r) =
                *(const int4*)(ol + row * OLS1 + cg * 8);
        }
    }
    // v columns (r>=64): transposed scalar stores, row-fast -> contiguous t runs
    for (int i = tid; i < 4096; i += 256) {
        const int col = i >> 6, row = i & 63;
        const int c0g = bn * 64 + col;
        const int h = (unsigned)c0g / 192u;
        const int r = c0g - h * 192;
        if (r >= 64) {
            const size_t g = (size_t)bm * 64 + row;
            const unsigned b = (unsigned)g / 49u;
            const unsigned t = (unsigned)g - b * 49u;
            vt[((size_t)(b * 8 + h) * 128 + (r - 64)) * TPAD + t] =
                ol[row * OLS1 + col];
        }
    }
}

__global__ __launch_bounds__(256, 4)
void qkv1_k(const void* hs, unsigned char* ws) {
    __shared__ __align__(16) bf16 ol[64 * OLS1];
    if (*(const int*)ws)
        qkv1_body<float>((const float*)hs, ws, ol);
    else
        qkv1_body<bf16>((const bf16*)hs, ws, ol);
}

// ======================= K2: attn + proj (light) ==============================
// Per block = one batch, 4 waves, 2 barriers/head:
//   stage vT tile (coalesced copy, no transpose) + Q/K frags direct from global
//   -> B1 -> scores MFMA + softmax (P into own ctx rows) -> PV MFMA -> B2 ->
//   proj partial accumulate (oacc persistent).
template <typename TO>
__device__ __forceinline__
void attn2_body(TO* __restrict__ out, unsigned char* ws, char* smem) {
    bf16*  ctxp = (bf16*)(smem + SM2_CTX);
    bf16*  vtl  = (bf16*)(smem + SM2_VT);
    float* abl  = (float*)(smem + SM2_AB);

    const bf16* qk = (const bf16*)(ws + OFF_QK);
    const bf16* pw = (const bf16*)(ws + OFF_PW2);
    const bf16* pb = (const bf16*)(ws + OFF_PB2);
    const bf16* ab = (const bf16*)(ws + OFF_AB2);

    const int b   = blockIdx.x;
    const int tid = threadIdx.x, l = tid & 63, w = tid >> 6;
    const int lr  = l & 15, lk = (l >> 4) * 8;
    const int cm  = (l >> 4) * 4, cn = l & 15;

    for (int i = tid; i < NHEADS * SEQ; i += 256) abl[i] = toF(ab[i]);
    // zero vT LDS cols 56..63 once (cols 49..55 zeroed in ws; cols 64.. unread)
    if (tid < 128)
        *(int4*)(vtl + tid * AVTS + TPAD) = int4{0, 0, 0, 0};

    // bias index: |r1-r2|*7 + |c1-c2|
    int rq[4], rr[4], cq[4], cr[4];
    #pragma unroll
    for (int r = 0; r < 4; ++r) {
        int row = 16 * w + cm + r; if (row > SEQ - 1) row = SEQ - 1;
        rq[r] = (row * 37) >> 8; rr[r] = row - rq[r] * 7;
    }
    #pragma unroll
    for (int j = 0; j < 4; ++j) {
        int col = 16 * j + cn; if (col > SEQ - 1) col = 0;
        cq[j] = (col * 37) >> 8; cr[j] = col - cq[j] * 7;
    }

    const int qrow = (16 * w + lr < SEQ) ? 16 * w + lr : SEQ - 1;
    int krow[4];
    #pragma unroll
    for (int j = 0; j < 4; ++j)
        krow[j] = (16 * j + lr < SEQ) ? 16 * j + lr : SEQ - 1;

    const bf16* qkb = qk + (size_t)b * SEQ * 512;
    const bf16* vtb0 = (const bf16*)(ws + OFF_VT) + (size_t)b * 8 * (128 * TPAD);

    f32x4 oacc[4][7] = {};
    const float scale = 0.17677669529663687f;

    for (int h = 0; h < NHEADS; ++h) {
        // stage vT tile: 896 int4 coalesced copies (rows 0..127 x cols 0..55)
        const bf16* vtb = vtb0 + (size_t)h * (128 * TPAD);
        #pragma unroll 2
        for (int i = tid; i < 896; i += 256) {
            const int row = (unsigned)i / 7u, c7 = i - row * 7;
            *(int4*)(vtl + row * AVTS + c7 * 8) =
                *(const int4*)(vtb + row * TPAD + c7 * 8);
        }
        // Q/K fragments direct global->reg
        const bf16x8 aq = load8(qkb + (size_t)qrow * 512 + h * 64 + lk);
        bf16x8 kb[4];
        #pragma unroll
        for (int j = 0; j < 4; ++j)
            kb[j] = load8(qkb + (size_t)krow[j] * 512 + h * 64 + 32 + lk);
        __syncthreads();   // B1: vT staged (also orders prev head's proj reads)

        // scores + softmax; P -> own ctx rows cols 0..63
        {
            f32x4 sacc[4] = {};
            #pragma unroll
            for (int j = 0; j < 4; ++j)
                sacc[j] = __builtin_amdgcn_mfma_f32_16x16x32_bf16(
                    aq, kb[j], sacc[j], 0, 0, 0);
            #pragma unroll
            for (int r = 0; r < 4; ++r) {
                const int row = 16 * w + cm + r;
                float v[4], e[4];
                float m = -3.0e38f;
                #pragma unroll
                for (int j = 0; j < 4; ++j) {
                    const int col = 16 * j + cn;
                    if (col < SEQ) {
                        int dy = rq[r] - cq[j]; dy = dy < 0 ? -dy : dy;
                        int dx = rr[r] - cr[j]; dx = dx < 0 ? -dx : dx;
                        v[j] = sacc[j][r] * scale + abl[h * SEQ + dy * 7 + dx];
                        m = fmaxf(m, v[j]);
                    } else v[j] = -3.0e38f;
                }
                m = fmaxf(m, __shfl_xor(m, 1));
                m = fmaxf(m, __shfl_xor(m, 2));
                m = fmaxf(m, __shfl_xor(m, 4));
                m = fmaxf(m, __shfl_xor(m, 8));
                float s = 0.f;
                #pragma unroll
                for (int j = 0; j < 4; ++j) {
                    e[j] = (16 * j + cn < SEQ) ? __expf(v[j] - m) : 0.f;
                    s += e[j];
                }
                s += __shfl_xor(s, 1);
                s += __shfl_xor(s, 2);
                s += __shfl_xor(s, 4);
                s += __shfl_xor(s, 8);
                const float inv = 1.f / s;
                #pragma unroll
                for (int j = 0; j < 4; ++j)
                    ctxp[row * ACS + 16 * j + cn] = __float2bfloat16(e[j] * inv);
            }
        }
        // PV: reads own P rows (in-wave) + staged vT; overwrite own ctx rows
        {
            const bf16x8 pa0 = *(const bf16x8*)(ctxp + (16 * w + lr) * ACS + lk);
            const bf16x8 pa1 = *(const bf16x8*)(ctxp + (16 * w + lr) * ACS + 32 + lk);
            f32x4 cacc[8] = {};
            #pragma unroll
            for (int n = 0; n < 8; ++n) {
                const bf16x8 vb = *(const bf16x8*)(vtl + (16 * n + lr) * AVTS + lk);
                cacc[n] = __builtin_amdgcn_mfma_f32_16x16x32_bf16(
                    pa0, vb, cacc[n], 0, 0, 0);
            }
            #pragma unroll
            for (int n = 0; n < 8; ++n) {
                const bf16x8 vb = *(const bf16x8*)(vtl + (16 * n + lr) * AVTS + 32 + lk);
                cacc[n] = __builtin_amdgcn_mfma_f32_16x16x32_bf16(
                    pa1, vb, cacc[n], 0, 0, 0);
            }
            #pragma unroll
            for (int n = 0; n < 8; ++n)
                #pragma unroll
                for (int r = 0; r < 4; ++r)
                    ctxp[(16 * w + cm + r) * ACS + 16 * n + cn] =
                        __float2bfloat16(cacc[n][r]);
        }
        __syncthreads();   // B2: ctx ready; vT consumed (safe to restage)

        // proj partial: oacc += ctx_h @ pw[:, h*128:+128]^T
        #pragma unroll
        for (int ks3 = 0; ks3 < 4; ++ks3) {
            bf16x8 bw[7], ac[4];
            #pragma unroll
            for (int j = 0; j < 7; ++j) {
                const int n = (w * 7 + j) * 16 + lr;
                bw[j] = load8(pw + (size_t)n * PDIM + h * 128 + ks3 * 32 + lk);
            }
            #pragma unroll
            for (int mf = 0; mf < 4; ++mf)
                ac[mf] = *(const bf16x8*)(ctxp + (16 * mf + lr) * ACS + ks3 * 32 + lk);
            #pragma unroll
            for (int mf = 0; mf < 4; ++mf)
                #pragma unroll
                for (int j = 0; j < 7; ++j)
                    oacc[mf][j] = __builtin_amdgcn_mfma_f32_16x16x32_bf16(
                        ac[mf], bw[j], oacc[mf][j], 0, 0, 0);
        }
        // no barrier: next head's B1 orders slow-wave proj reads vs P writes
    }

    #pragma unroll
    for (int j = 0; j < 7; ++j) {
        const int col = w * 112 + j * 16 + cn;
        const float pbv = toF(pb[col]);
        #pragma unroll
        for (int mf = 0; mf < 4; ++mf)
            #pragma unroll
            for (int r = 0; r < 4; ++r) {
                const int row = 16 * mf + cm + r;
                if (row < SEQ)
                    storeT(out + ((size_t)b * SEQ + row) * CDIM + col,
                           oacc[mf][j][r] + pbv);
            }
    }
}

__global__ __launch_bounds__(256, 2)
void attn2_k(void* out, unsigned char* ws) {
    __shared__ __align__(16) char smem[SM2_SZ];
    if (*(const int*)ws)
        attn2_body<float>((float*)out, ws, smem);
    else
        attn2_body<bf16>((bf16*)out, ws, smem);
}

// ======================= fallback path (round-2 fused kernel) =================
__device__ __forceinline__ void cvt_arr(const float* __restrict__ src,
                                        bf16* __restrict__ dst, size_t n4,
                                        size_t tid, size_t np) {
    for (size_t i = tid; i < n4; i += np) {
        f32x4 v = ((const f32x4*)src)[i];
        short4 o;
        o.x = f2s(v[0]); o.y = f2s(v[1]); o.z = f2s(v[2]); o.w = f2s(v[3]);
        ((short4*)dst)[i] = o;
    }
}

__global__ void convert_inputs(const float* hs, const float* qw, const float* qb,
                               const float* pw, const float* pb, const float* ab,
                               unsigned char* ws, const int* flag) {
    if (*flag == 0) return;
    const size_t tid = (size_t)blockIdx.x * blockDim.x + threadIdx.x;
    const size_t np  = (size_t)gridDim.x * blockDim.x;
    cvt_arr(hs, (bf16*)(ws + OFF_HS), kNhs / 4, tid, np);
    cvt_arr(qw, (bf16*)(ws + OFF_QW), kNqw / 4, tid, np);
    cvt_arr(qb, (bf16*)(ws + OFF_QB), kNqb / 4, tid, np);
    cvt_arr(pw, (bf16*)(ws + OFF_PW), kNpw / 4, tid, np);
    cvt_arr(pb, (bf16*)(ws + OFF_PB), kNpb / 4, tid, np);
    cvt_arr(ab, (bf16*)(ws + OFF_AB), kNab / 4, tid, np);
}

template <typename T, typename TO>
__device__ __forceinline__
void body(const T* __restrict__ hs, const T* __restrict__ qkv_w,
          const T* __restrict__ qkv_b, const T* __restrict__ proj_w,
          const T* __restrict__ proj_b, const T* __restrict__ ab,
          TO* __restrict__ out, char* smem) {
    bf16*  ctxp = (bf16*)(smem + SM_CTX);
    bf16*  ql   = (bf16*)(smem + SM_QL);
    bf16*  kl   = (bf16*)(smem + SM_KL);
    bf16*  vtl  = (bf16*)(smem + SM_VT);
    float* abl  = (float*)(smem + SM_AB);

    const int b   = blockIdx.x;
    const int tid = threadIdx.x;
    const int l   = tid & 63;
    const int w   = tid >> 6;
    const int lr  = l & 15;
    const int lk  = (l >> 4) * 8;
    const int cm  = (l >> 4) * 4;
    const int cn  = l & 15;

    for (int i = tid; i < NHEADS * SEQ; i += 256) abl[i] = toF(ab[i]);
    for (int i = tid; i < 128 * (64 - SEQ); i += 256) {
        const int d = i / (64 - SEQ), t = SEQ + i % (64 - SEQ);
        vtl[d * VTS + t] = __float2bfloat16(0.f);
    }

    int rq[4], rr[4], cq[4], cr[4];
    #pragma unroll
    for (int r = 0; r < 4; ++r) {
        int row = 16 * w + cm + r; if (row > SEQ - 1) row = SEQ - 1;
        rq[r] = (row * 37) >> 8; rr[r] = row - rq[r] * 7;
    }
    #pragma unroll
    for (int j = 0; j < 4; ++j) {
        int col = 16 * j + cn; if (col > SEQ - 1) col = 0;
        cq[j] = (col * 37) >> 8; cr[j] = col - cq[j] * 7;
    }

    f32x4 oacc[4][7] = {};
    const float scale = 0.17677669529663687f;
    const T* hsb = hs + (size_t)b * SEQ * CDIM;

    for (int h = 0; h < NHEADS; ++h) {
        f32x4 qacc[3][4] = {};
        bf16x8 af0[4], bf0[3], af1[4], bf1[3];
        auto LOADA = [&](int ks, bf16x8* af, bf16x8* bfr) {
            const int k0 = ks * 32;
            #pragma unroll
            for (int mf = 0; mf < 4; ++mf) {
                int row = 16 * mf + lr; if (row > SEQ - 1) row = SEQ - 1;
                af[mf] = load8(hsb + row * CDIM + k0 + lk);
            }
            #pragma unroll
            for (int j = 0; j < 3; ++j) {
                const int n = h * 192 + (3 * w + j) * 16 + lr;
                bfr[j] = load8(qkv_w + (size_t)n * CDIM + k0 + lk);
            }
        };
        auto MFMAA = [&](bf16x8* af, bf16x8* bfr) {
            #pragma unroll
            for (int j = 0; j < 3; ++j)
                #pragma unroll
                for (int mf = 0; mf < 4; ++mf)
                    qacc[j][mf] = __builtin_amdgcn_mfma_f32_16x16x32_bf16(
                        af[mf], bfr[j], qacc[j][mf], 0, 0, 0);
        };
        LOADA(0, af0, bf0);
        LOADA(1, af1, bf1);
        #pragma unroll
        for (int ks = 0; ks < 14; ks += 2) {
            MFMAA(af0, bf0);
            if (ks + 2 < 14) LOADA(ks + 2, af0, bf0);
            MFMAA(af1, bf1);
            if (ks + 3 < 14) LOADA(ks + 3, af1, bf1);
        }
        #pragma unroll
        for (int j = 0; j < 3; ++j) {
            const int c = (3 * w + j) * 16 + cn;
            const float bv = toF(qkv_b[h * 192 + c]);
            #pragma unroll
            for (int mf = 0; mf < 4; ++mf)
                #pragma unroll
                for (int r = 0; r < 4; ++r) {
                    const int row = 16 * mf + cm + r;
                    const float v = qacc[j][mf][r] + bv;
                    if (row < SEQ) {
                        if (c < 32)      ql[row * QS + c] = __float2bfloat16(v);
                        else if (c < 64) kl[row * QS + (c - 32)] = __float2bfloat16(v);
                        else             vtl[(c - 64) * VTS + row] = __float2bfloat16(v);
                    }
                }
        }
        __syncthreads();

        {
            const bf16x8 aq = *(const bf16x8*)(ql + (16 * w + lr) * QS + lk);
            f32x4 sacc[4] = {};
            #pragma unroll
            for (int j = 0; j < 4; ++j) {
                const bf16x8 kb = *(const bf16x8*)(kl + (16 * j + lr) * QS + lk);
                sacc[j] = __builtin_amdgcn_mfma_f32_16x16x32_bf16(
                    aq, kb, sacc[j], 0, 0, 0);
            }
            #pragma unroll
            for (int r = 0; r < 4; ++r) {
                const int row = 16 * w + cm + r;
                float v[4], e[4];
                float m = -3.0e38f;
                #pragma unroll
                for (int j = 0; j < 4; ++j) {
                    const int col = 16 * j + cn;
                    if (col < SEQ) {
                        int dy = rq[r] - cq[j]; dy = dy < 0 ? -dy : dy;
                        int dx = rr[r] - cr[j]; dx = dx < 0 ? -dx : dx;
                        v[j] = sacc[j][r] * scale + abl[h * SEQ + dy * 7 + dx];
                        m = fmaxf(m, v[j]);
                    } else v[j] = -3.0e38f;
                }
                m = fmaxf(m, __shfl_xor(m, 1));
                m = fmaxf(m, __shfl_xor(m, 2));
                m = fmaxf(m, __shfl_xor(m, 4));
                m = fmaxf(m, __shfl_xor(m, 8));
                float s = 0.f;
                #pragma unroll
                for (int j = 0; j < 4; ++j) {
                    e[j] = (16 * j + cn < SEQ) ? __expf(v[j] - m) : 0.f;
                    s += e[j];
                }
                s += __shfl_xor(s, 1);
                s += __shfl_xor(s, 2);
                s += __shfl_xor(s, 4);
                s += __shfl_xor(s, 8);
                const float inv = 1.f / s;
                #pragma unroll
                for (int j = 0; j < 4; ++j)
                    ctxp[row * CS + 16 * j + cn] = __float2bfloat16(e[j] * inv);
            }
        }

        {
            const bf16x8 pa0 = *(const bf16x8*)(ctxp + (16 * w + lr) * CS + lk);
            const bf16x8 pa1 = *(const bf16x8*)(ctxp + (16 * w + lr) * CS + 32 + lk);
            f32x4 cacc[8] = {};
            #pragma unroll
            for (int n = 0; n < 8; ++n) {
                const bf16x8 vb0 = *(const bf16x8*)(vtl + (16 * n + lr) * VTS + lk);
                cacc[n] = __builtin_amdgcn_mfma_f32_16x16x32_bf16(
                    pa0, vb0, cacc[n], 0, 0, 0);
            }
            #pragma unroll
            for (int n = 0; n < 8; ++n) {
                const bf16x8 vb1 = *(const bf16x8*)(vtl + (16 * n + lr) * VTS + 32 + lk);
                cacc[n] = __builtin_amdgcn_mfma_f32_16x16x32_bf16(
                    pa1, vb1, cacc[n], 0, 0, 0);
            }
            #pragma unroll
            for (int n = 0; n < 8; ++n)
                #pragma unroll
                for (int r = 0; r < 4; ++r)
                    ctxp[(16 * w + cm + r) * CS + 16 * n + cn] =
                        __float2bfloat16(cacc[n][r]);
        }
        __syncthreads();

        #pragma unroll
        for (int ks3 = 0; ks3 < 4; ++ks3) {
            bf16x8 bw[7], ac[4];
            #pragma unroll
            for (int j = 0; j < 7; ++j) {
                const int n = (w * 7 + j) * 16 + lr;
                bw[j] = load8(proj_w + (size_t)n * PDIM + h * 128 + ks3 * 32 + lk);
            }
            #pragma unroll
            for (int mf = 0; mf < 4; ++mf)
                ac[mf] = *(const bf16x8*)(ctxp + (16 * mf + lr) * CS + ks3 * 32 + lk);
            #pragma unroll
            for (int mf = 0; mf < 4; ++mf)
                #pragma unroll
                for (int j = 0; j < 7; ++j)
                    oacc[mf][j] = __builtin_amdgcn_mfma_f32_16x16x32_bf16(
                        ac[mf], bw[j], oacc[mf][j], 0, 0, 0);
        }
    }

    #pragma unroll
    for (int j = 0; j < 7; ++j) {
        const int col = w * 112 + j * 16 + cn;
        const float pbv = toF(proj_b[col]);
        #pragma unroll
        for (int mf = 0; mf < 4; ++mf)
            #pragma unroll
            for (int r = 0; r < 4; ++r) {
                const int row = 16 * mf + cm + r;
                if (row < SEQ)
                    storeT(out + ((size_t)b * SEQ + row) * CDIM + col,
                           oacc[mf][j][r] + pbv);
            }
    }
}

__global__ __launch_bounds__(256, 2)
void fused_effattn(const void* hs, const void* qkv_w, const void* qkv_b,
                   const void* proj_w, const void* proj_b, const void* ab,
                   const int* idxs, void* out, unsigned char* ws, int use_ws) {
    __shared__ __align__(16) char smem[SM_SZ];
    const int f = *(const int*)ws;
    if (f) {
        if (use_ws) {
            body<bf16, float>((const bf16*)(ws + OFF_HS), (const bf16*)(ws + OFF_QW),
                              (const bf16*)(ws + OFF_QB), (const bf16*)(ws + OFF_PW),
                              (const bf16*)(ws + OFF_PB), (const bf16*)(ws + OFF_AB),
                              (float*)out, smem);
        } else {
            body<float, float>((const float*)hs, (const float*)qkv_w,
                               (const float*)qkv_b, (const float*)proj_w,
                               (const float*)proj_b, (const float*)ab,
                               (float*)out, smem);
        }
    } else {
        body<bf16, bf16>((const bf16*)hs, (const bf16*)qkv_w, (const bf16*)qkv_b,
                         (const bf16*)proj_w, (const bf16*)proj_b, (const bf16*)ab,
                         (bf16*)out, smem);
    }
}

// ======================= launcher =============================================
extern "C" void kernel_launch(void* const* d_in, const int* in_sizes, int n_in,
                              void* d_out, int out_size, void* d_ws, size_t ws_size,
                              hipStream_t stream) {
    unsigned char* ws = (unsigned char*)d_ws;
    detect_dtype<<<1, 64, 0, stream>>>((const unsigned int*)d_in[1], (int*)ws);
    if (ws_size >= WS_A) {
        prep_k<<<dim3(2048), dim3(256), 0, stream>>>(
            d_in[1], d_in[2], d_in[3], d_in[4], d_in[5], ws);
        qkv1_k<<<dim3(K1_MT * K1_NT), dim3(256), 0, stream>>>(d_in[0], ws);
        attn2_k<<<dim3(NB), dim3(256), 0, stream>>>(d_out, ws);
    } else {
        const int use_ws = (ws_size >= WS_NEEDED) ? 1 : 0;
        if (use_ws)
            convert_inputs<<<dim3(2048), dim3(256), 0, stream>>>(
                (const float*)d_in[0], (const float*)d_in[1], (const float*)d_in[2],
                (const float*)d_in[3], (const float*)d_in[4], (const float*)d_in[5],
                ws, (const int*)ws);
        fused_effattn<<<dim3(2048), dim3(256), 0, stream>>>(
            d_in[0], d_in[1], d_in[2], d_in[3], d_in[4], d_in[5],
            (const int*)d_in[6], d_out, ws, use_ws);
    }
}